// Round 4
// baseline (125.422 us; speedup 1.0000x reference)
//
#include <hip/hip_runtime.h>
#include <math.h>

#define CH_STRIDE (512 * 512)

// f32 DCT matrix = float32(float64 0.5*cos((2x+1)u*pi/16), row0 /sqrt2) — matches asarray(D, float32)
static constexpr float DMc[8][8] = {
  { 0.35355339059327373f, 0.35355339059327373f, 0.35355339059327373f, 0.35355339059327373f,
    0.35355339059327373f, 0.35355339059327373f, 0.35355339059327373f, 0.35355339059327373f},
  { 0.49039264020161522f, 0.41573480615127262f, 0.27778511650980111f, 0.09754516100806413f,
   -0.09754516100806413f,-0.27778511650980111f,-0.41573480615127262f,-0.49039264020161522f},
  { 0.46193976625564337f, 0.19134171618254489f,-0.19134171618254489f,-0.46193976625564337f,
   -0.46193976625564337f,-0.19134171618254489f, 0.19134171618254489f, 0.46193976625564337f},
  { 0.41573480615127262f,-0.09754516100806413f,-0.49039264020161522f,-0.27778511650980111f,
    0.27778511650980111f, 0.49039264020161522f, 0.09754516100806413f,-0.41573480615127262f},
  { 0.35355339059327373f,-0.35355339059327373f,-0.35355339059327373f, 0.35355339059327373f,
    0.35355339059327373f,-0.35355339059327373f,-0.35355339059327373f, 0.35355339059327373f},
  { 0.27778511650980111f,-0.49039264020161522f, 0.09754516100806413f, 0.41573480615127262f,
   -0.41573480615127262f,-0.09754516100806413f, 0.49039264020161522f,-0.27778511650980111f},
  { 0.19134171618254489f,-0.46193976625564337f, 0.46193976625564337f,-0.19134171618254489f,
   -0.19134171618254489f, 0.46193976625564337f,-0.46193976625564337f, 0.19134171618254489f},
  { 0.09754516100806413f,-0.27778511650980111f, 0.41573480615127262f,-0.49039264020161522f,
    0.49039264020161522f,-0.41573480615127262f, 0.27778511650980111f,-0.09754516100806413f},
};

// q = float32(table) * 0.5f — exact halves. [0..63]=Y[u][v], [64..127]=C.
static constexpr float QTABc[128] = {
   8.0f,  5.5f,  5.0f,  8.0f, 12.0f, 20.0f, 25.5f, 30.5f,
   6.0f,  6.0f,  7.0f,  9.5f, 13.0f, 29.0f, 30.0f, 27.5f,
   7.0f,  6.5f,  8.0f, 12.0f, 20.0f, 28.5f, 34.5f, 28.0f,
   7.0f,  8.5f, 11.0f, 14.5f, 25.5f, 43.5f, 40.0f, 31.0f,
   9.0f, 11.0f, 18.5f, 28.0f, 34.0f, 54.5f, 51.5f, 38.5f,
  12.0f, 17.5f, 27.5f, 32.0f, 40.5f, 52.0f, 56.5f, 46.0f,
  24.5f, 32.0f, 39.0f, 43.5f, 51.5f, 60.5f, 60.0f, 50.5f,
  36.0f, 46.0f, 47.5f, 49.0f, 56.0f, 50.0f, 51.5f, 49.5f,

   8.5f,  9.0f, 12.0f, 23.5f, 49.5f, 49.5f, 49.5f, 49.5f,
   9.0f, 10.5f, 13.0f, 33.0f, 49.5f, 49.5f, 49.5f, 49.5f,
  12.0f, 13.0f, 28.0f, 49.5f, 49.5f, 49.5f, 49.5f, 49.5f,
  23.5f, 33.0f, 49.5f, 49.5f, 49.5f, 49.5f, 49.5f, 49.5f,
  49.5f, 49.5f, 49.5f, 49.5f, 49.5f, 49.5f, 49.5f, 49.5f,
  49.5f, 49.5f, 49.5f, 49.5f, 49.5f, 49.5f, 49.5f, 49.5f,
  49.5f, 49.5f, 49.5f, 49.5f, 49.5f, 49.5f, 49.5f, 49.5f,
  49.5f, 49.5f, 49.5f, 49.5f, 49.5f, 49.5f, 49.5f, 49.5f,
};

// correctly-rounded f32 ops, no contraction — each maps to one numpy C op
__device__ __forceinline__ float fm(float a, float b) { return __fmul_rn(a, b); }
__device__ __forceinline__ float fa(float a, float b) { return __fadd_rn(a, b); }
__device__ __forceinline__ float fs(float a, float b) { return __fsub_rn(a, b); }
__device__ __forceinline__ float fd(float a, float b) { return __fdiv_rn(a, b); }

// Packed FP32 (CDNA VOPP v_pk_mul_f32 / v_pk_add_f32): TWO independent correctly-rounded
// f32 ops per instruction. contract(off) forbids mul+add fusion, so each packed lane is
// bit-identical to the scalar fm/fa it replaces. If the backend scalarizes, results are
// still bit-identical (just no speedup).
typedef float v2f __attribute__((ext_vector_type(2)));
__device__ __forceinline__ v2f mk2(float a, float b) { v2f r; r.x = a; r.y = b; return r; }
__device__ __forceinline__ v2f pm2(v2f a, v2f b) {
#pragma clang fp contract(off)
  return a * b;
}
__device__ __forceinline__ v2f pa2(v2f a, v2f b) {
#pragma clang fp contract(off)
  return a + b;
}

// One workgroup = one 32x32 pixel tile = 3 waves (192 threads).
//   24 DCT blocks (16 Y + 4 Cb + 4 Cr) x 8 rows = 192 row-tasks = ALL waves fully active.
//   blk = tid>>3 → wave = blk>>3: einsum1→einsum2 dependency (Cq) is same-wave only →
//   no __syncthreads between them (per-wave LDS ops complete in order; fence + lgkmcnt(0)).
//   Chroma recon aliases the chroma input buffer (same-wave in-order) → LDS 14.1KB.
//   Einsum accumulator chains are packed pairwise into v2f (VOPP packed FP32): independent
//   chains only, each lane keeps its exact scalar term order — bit-identical, ~half the issue.
//
//   LAUNCH BOUNDS: (192, 4) — NOT (192, 8). R2 post-mortem: min-waves-per-EU=8 forced
//   VGPR=32 → scratch spill catastrophe. Cap loosely; natural allocation is ~64-84 VGPR.
__global__ __launch_bounds__(192, 4)
void jpeg_kernel(const float* __restrict__ x, float* __restrict__ out) {
  const int tid = threadIdx.x;
  const int q  = blockIdx.x;           // 0..4095
  const int b  = q >> 8;               // image 0..15
  const int qq = q & 255;
  const int row0 = (qq >> 4) << 5;     // 32-px tile row
  const int col0 = (qq & 15) << 5;

  __shared__ __align__(16) float Ys[32][36];   // centered Y, then recon y_r (in-place per wave)
  __shared__ __align__(16) float Cb[16][20];   // subsampled -128, then recon cbm (in-place, wave 2)
  __shared__ __align__(16) float Cr[16][20];
  __shared__ __align__(16) float Cq[24][8][9]; // quantized coefs [blk][u][v] (stride 9: de-conflicts across blk)

  // ---------------- Stage 1: load, clip, *255, color convert (strict f32, no FMA) ----------------
  // quad qd (0..255): pr=qd>>3 (pixel row), pc=(qd&7)*4. Threads handle qd=tid; wave 0 also qd=192+tid.
  auto stage1 = [&](int qd) {
    const int pr = qd >> 3;
    const int pc = (qd & 7) << 2;
    const size_t ib = ((((size_t)b * 3) * 512 + (size_t)(row0 + pr)) * 512) + (size_t)(col0 + pc);
    float4 rv = *(const float4*)(x + ib);
    float4 gv = *(const float4*)(x + ib + CH_STRIDE);
    float4 bv = *(const float4*)(x + ib + 2 * CH_STRIDE);
    float xr[4] = {rv.x, rv.y, rv.z, rv.w};
    float xg[4] = {gv.x, gv.y, gv.z, gv.w};
    float xb[4] = {bv.x, bv.y, bv.z, bv.w};
    float yo[4], cbv[4], crv[4];
#pragma unroll
    for (int i = 0; i < 4; ++i) {
      float r  = fm(fminf(fmaxf(xr[i], 0.0f), 1.0f), 255.0f);
      float g  = fm(fminf(fmaxf(xg[i], 0.0f), 1.0f), 255.0f);
      float bb = fm(fminf(fmaxf(xb[i], 0.0f), 1.0f), 255.0f);
      float y  = fa(fa(fm(0.299f, r), fm(0.587f, g)), fm(0.114f, bb));
      yo[i]  = fs(y, 128.0f);
      cbv[i] = fa(fa(fs(fm(-0.168736f, r), fm(0.331264f, g)), fm(0.5f, bb)), 128.0f);
      crv[i] = fa(fs(fs(fm(0.5f, r), fm(0.418688f, g)), fm(0.081312f, bb)), 128.0f);
    }
    *(float4*)&Ys[pr][pc] = make_float4(yo[0], yo[1], yo[2], yo[3]);

    // chroma 2x2 mean — pairwise (c00+c01)+(c10+c11), exact /4 as *0.25f (power-of-2, bit-equal)
    float cbh0 = fa(cbv[0], cbv[1]), cbh1 = fa(cbv[2], cbv[3]);
    float crh0 = fa(crv[0], crv[1]), crh1 = fa(crv[2], crv[3]);
    float pcb0 = __shfl_xor(cbh0, 8, 64);   // partner = adjacent pixel row, same cols (same wave)
    float pcb1 = __shfl_xor(cbh1, 8, 64);
    float pcr0 = __shfl_xor(crh0, 8, 64);
    float pcr1 = __shfl_xor(crh1, 8, 64);
    if (((qd >> 3) & 1) == 0) {             // even pixel row: owns the 2x2 output
      const int ii = pr >> 1, jc = pc >> 1;
      Cb[ii][jc]     = fs(fm(fa(cbh0, pcb0), 0.25f), 128.0f);
      Cb[ii][jc + 1] = fs(fm(fa(cbh1, pcb1), 0.25f), 128.0f);
      Cr[ii][jc]     = fs(fm(fa(crh0, pcr0), 0.25f), 128.0f);
      Cr[ii][jc + 1] = fs(fm(fa(crh1, pcr1), 0.25f), 128.0f);
    }
  };
  stage1(tid);
  if (tid < 64) stage1(192 + tid);        // whole wave 0 → shfl pairs stay intact
  __syncthreads();

  // Task mapping: blk = tid>>3 (0..15 Y, 16..19 Cb, 20..23 Cr), j = tid&7 (coef row u / recon row x)
  const int  blk = tid >> 3;
  const int  j   = tid & 7;
  const bool isY = blk < 16;
  const float* src;   // 8x8 block base in LDS
  float*       wdst;  // recon row dest (aliases src buffer; same-wave in-order → safe)
  int ld;
  const float* qr = QTABc + j * 8;
  if (isY) {
    const int by = blk >> 2, bx = blk & 3;
    src = &Ys[by * 8][bx * 8];  wdst = &Ys[by * 8 + j][bx * 8];  ld = 36;
  } else if (blk < 20) {
    const int c = blk - 16, cy = c >> 1, cx = c & 1;
    src = &Cb[cy * 8][cx * 8];  wdst = &Cb[cy * 8 + j][cx * 8];  ld = 20;  qr += 64;
  } else {
    const int c = blk - 20, cy = c >> 1, cx = c & 1;
    src = &Cr[cy * 8][cx * 8];  wdst = &Cr[cy * 8 + j][cx * 8];  ld = 20;  qr += 64;
  }

  // ======= einsum1 'bhwxy,ux,vy->bhwuv' — np c_einsum outstride0_three, SIMD 4-lane =======
  // Packed form: SIMD lanes (s0,s1) and (s2,s3) ride in v2f pairs sA/sB. Per lane the term
  // sequence is EXACTLY the original m=0..15: fa(s, fm(t0[4m+l], DMc[v][(4m+l)&7])), with
  // t0[8xx+yy]=fm(blk[xx][yy],DMc[j][xx]); coef = fa(fa(s0,s1),fa(s2,s3)) — bit-identical.
  {
    float dj[8];
#pragma unroll
    for (int xx = 0; xx < 8; ++xx) dj[xx] = DMc[j][xx];
    v2f sA[8], sB[8];
#pragma unroll
    for (int v = 0; v < 8; ++v) { sA[v] = mk2(0.0f, 0.0f); sB[v] = mk2(0.0f, 0.0f); }
    const float* srow = src;
#pragma unroll
    for (int xx = 0; xx < 8; ++xx) {
      float4 aq = *(const float4*)(srow);
      float4 bq = *(const float4*)(srow + 4);
      srow += ld;
      v2f djp = mk2(dj[xx], dj[xx]);
      v2f t01 = pm2(mk2(aq.x, aq.y), djp);   // t0r[0],t0r[1]
      v2f t23 = pm2(mk2(aq.z, aq.w), djp);   // t0r[2],t0r[3]
      v2f t45 = pm2(mk2(bq.x, bq.y), djp);   // t0r[4],t0r[5]
      v2f t67 = pm2(mk2(bq.z, bq.w), djp);   // t0r[6],t0r[7]
#pragma unroll
      for (int v = 0; v < 8; ++v) {
        sA[v] = pa2(sA[v], pm2(t01, mk2(DMc[v][0], DMc[v][1])));   // m = 2*xx   (lanes 0,1)
        sB[v] = pa2(sB[v], pm2(t23, mk2(DMc[v][2], DMc[v][3])));   //            (lanes 2,3)
        sA[v] = pa2(sA[v], pm2(t45, mk2(DMc[v][4], DMc[v][5])));   // m = 2*xx+1 (lanes 0,1)
        sB[v] = pa2(sB[v], pm2(t67, mk2(DMc[v][6], DMc[v][7])));   //            (lanes 2,3)
      }
    }
    float* cq = &Cq[blk][j][0];
#pragma unroll
    for (int v = 0; v < 8; ++v) {
      float coef = fa(fa(sA[v].x, sA[v].y), fa(sB[v].x, sB[v].y));  // hadd tree
      float qv = qr[v];
      cq[v] = fm(rintf(fd(coef, qv)), qv);                          // round half-even, f32 div
    }
  }

  // Cq[blk] producers and consumers are the SAME wave (blk>>3 == tid>>6): per-wave LDS ops
  // complete in order, so no block barrier — just a compiler fence + drain of our own ds ops.
  asm volatile("s_waitcnt lgkmcnt(0)" ::: "memory");

  // ======= einsum2 'bhwuv,ux,vy->bhwxy' — per-element scalar chain, u outer / v inner =======
  // Packed over yy pairs: accP[t] = (acc[2t], acc[2t+1]); per (u,v) one pk_mul+pk_add per pair.
  // Each acc lane receives its (u,v)-lexicographic term sequence fa(acc, fm(t2r[v], DMc[v][yy]))
  // exactly as the scalar version — bit-identical.
  {
    v2f accP[4];
#pragma unroll
    for (int t = 0; t < 4; ++t) accP[t] = mk2(0.0f, 0.0f);
    const float* cqb = &Cq[blk][0][0];
#pragma unroll
    for (int u = 0; u < 8; ++u) {
      float du = DMc[u][j];
      v2f t2s[8];
#pragma unroll
      for (int v = 0; v < 8; ++v) {
        float t = fm(cqb[u * 9 + v], du);    // t2r[v] = fl(coef[u][v] * D[u][x=j])
        t2s[v] = mk2(t, t);
      }
#pragma unroll
      for (int v = 0; v < 8; ++v) {
#pragma unroll
        for (int t = 0; t < 4; ++t)
          accP[t] = pa2(accP[t], pm2(t2s[v], mk2(DMc[v][2 * t], DMc[v][2 * t + 1])));
      }
    }
    float r0[8];
#pragma unroll
    for (int t = 0; t < 4; ++t) {
      float recA = fa(accP[t].x, 128.0f);
      float recB = fa(accP[t].y, 128.0f);
      r0[2 * t]     = isY ? recA : fs(recA, 128.0f);               // y_r  /  cbm = cb_u - 128
      r0[2 * t + 1] = isY ? recB : fs(recB, 128.0f);
    }
    *(float4*)(wdst)     = make_float4(r0[0], r0[1], r0[2], r0[3]);
    *(float4*)(wdst + 4) = make_float4(r0[4], r0[5], r0[6], r0[7]);
  }
  __syncthreads();

  // ---------------- Stage 5: upsample, YCbCr->RGB (strict), clip, /255, wrapper ----------------
  auto stage5 = [&](int qd) {
    const int pr = qd >> 3;
    const int pc = (qd & 7) << 2;
    const size_t ib = ((((size_t)b * 3) * 512 + (size_t)(row0 + pr)) * 512) + (size_t)(col0 + pc);
    float4 rv = *(const float4*)(x + ib);          // re-load x (L1/L2-hot)
    float4 gv = *(const float4*)(x + ib + CH_STRIDE);
    float4 bv = *(const float4*)(x + ib + 2 * CH_STRIDE);
    float xr[4] = {rv.x, rv.y, rv.z, rv.w};
    float xg[4] = {gv.x, gv.y, gv.z, gv.w};
    float xb[4] = {bv.x, bv.y, bv.z, bv.w};
    float ro[4], go[4], bo[4];
    const int hr = pr >> 1;
#pragma unroll
    for (int i = 0; i < 4; ++i) {
      float y_r = Ys[pr][pc + i];
      float cbm = Cb[hr][(pc + i) >> 1];
      float crm = Cr[hr][(pc + i) >> 1];
      float r2 = fa(y_r, fm(1.402f, crm));
      float g2 = fs(fs(y_r, fm(0.344136f, cbm)), fm(0.714136f, crm));
      float b2 = fa(y_r, fm(1.772f, cbm));
      float jr = fd(fminf(fmaxf(r2, 0.0f), 255.0f), 255.0f);
      float jg = fd(fminf(fmaxf(g2, 0.0f), 255.0f), 255.0f);
      float jb = fd(fminf(fmaxf(b2, 0.0f), 255.0f), 255.0f);
      ro[i] = fa(xr[i], fs(jr, xr[i]));   // x + (jpeg - x), original unclipped x
      go[i] = fa(xg[i], fs(jg, xg[i]));
      bo[i] = fa(xb[i], fs(jb, xb[i]));
    }
    *(float4*)(out + ib)                 = make_float4(ro[0], ro[1], ro[2], ro[3]);
    *(float4*)(out + ib + CH_STRIDE)     = make_float4(go[0], go[1], go[2], go[3]);
    *(float4*)(out + ib + 2 * CH_STRIDE) = make_float4(bo[0], bo[1], bo[2], bo[3]);
  };
  stage5(tid);
  if (tid < 64) stage5(192 + tid);
}

extern "C" void kernel_launch(void* const* d_in, const int* in_sizes, int n_in,
                              void* d_out, int out_size, void* d_ws, size_t ws_size,
                              hipStream_t stream) {
  const float* x = (const float*)d_in[0];
  float* out = (float*)d_out;
  jpeg_kernel<<<dim3(4096), dim3(192), 0, stream>>>(x, out);
}

// Round 5
// 125.386 us; speedup vs baseline: 1.0003x; 1.0003x over previous
//
#include <hip/hip_runtime.h>
#include <math.h>

#define CH_STRIDE (512 * 512)

// f32 DCT matrix = float32(float64 0.5*cos((2x+1)u*pi/16), row0 /sqrt2) — matches asarray(D, float32)
static constexpr float DMc[8][8] = {
  { 0.35355339059327373f, 0.35355339059327373f, 0.35355339059327373f, 0.35355339059327373f,
    0.35355339059327373f, 0.35355339059327373f, 0.35355339059327373f, 0.35355339059327373f},
  { 0.49039264020161522f, 0.41573480615127262f, 0.27778511650980111f, 0.09754516100806413f,
   -0.09754516100806413f,-0.27778511650980111f,-0.41573480615127262f,-0.49039264020161522f},
  { 0.46193976625564337f, 0.19134171618254489f,-0.19134171618254489f,-0.46193976625564337f,
   -0.46193976625564337f,-0.19134171618254489f, 0.19134171618254489f, 0.46193976625564337f},
  { 0.41573480615127262f,-0.09754516100806413f,-0.49039264020161522f,-0.27778511650980111f,
    0.27778511650980111f, 0.49039264020161522f, 0.09754516100806413f,-0.41573480615127262f},
  { 0.35355339059327373f,-0.35355339059327373f,-0.35355339059327373f, 0.35355339059327373f,
    0.35355339059327373f,-0.35355339059327373f,-0.35355339059327373f, 0.35355339059327373f},
  { 0.27778511650980111f,-0.49039264020161522f, 0.09754516100806413f, 0.41573480615127262f,
   -0.41573480615127262f,-0.09754516100806413f, 0.49039264020161522f,-0.27778511650980111f},
  { 0.19134171618254489f,-0.46193976625564337f, 0.46193976625564337f,-0.19134171618254489f,
   -0.19134171618254489f, 0.46193976625564337f,-0.46193976625564337f, 0.19134171618254489f},
  { 0.09754516100806413f,-0.27778511650980111f, 0.41573480615127262f,-0.49039264020161522f,
    0.49039264020161522f,-0.41573480615127262f, 0.27778511650980111f,-0.09754516100806413f},
};

// DMcT[x][u] = DMc[u][x] — so einsum2's column-of-DMc becomes a contiguous row load.
static constexpr float DMcT[8][8] = {
  { 0.35355339059327373f, 0.49039264020161522f, 0.46193976625564337f, 0.41573480615127262f,
    0.35355339059327373f, 0.27778511650980111f, 0.19134171618254489f, 0.09754516100806413f},
  { 0.35355339059327373f, 0.41573480615127262f, 0.19134171618254489f,-0.09754516100806413f,
   -0.35355339059327373f,-0.49039264020161522f,-0.46193976625564337f,-0.27778511650980111f},
  { 0.35355339059327373f, 0.27778511650980111f,-0.19134171618254489f,-0.49039264020161522f,
   -0.35355339059327373f, 0.09754516100806413f, 0.46193976625564337f, 0.41573480615127262f},
  { 0.35355339059327373f, 0.09754516100806413f,-0.46193976625564337f,-0.27778511650980111f,
    0.35355339059327373f, 0.41573480615127262f,-0.19134171618254489f,-0.49039264020161522f},
  { 0.35355339059327373f,-0.09754516100806413f,-0.46193976625564337f, 0.27778511650980111f,
    0.35355339059327373f,-0.41573480615127262f,-0.19134171618254489f, 0.49039264020161522f},
  { 0.35355339059327373f,-0.27778511650980111f,-0.19134171618254489f, 0.49039264020161522f,
   -0.35355339059327373f,-0.09754516100806413f, 0.46193976625564337f,-0.41573480615127262f},
  { 0.35355339059327373f,-0.41573480615127262f, 0.19134171618254489f, 0.09754516100806413f,
   -0.35355339059327373f, 0.49039264020161522f,-0.46193976625564337f, 0.27778511650980111f},
  { 0.35355339059327373f,-0.49039264020161522f, 0.46193976625564337f,-0.41573480615127262f,
    0.35355339059327373f,-0.27778511650980111f, 0.19134171618254489f,-0.09754516100806413f},
};

// q = float32(table) * 0.5f — exact halves. [0..63]=Y[u][v], [64..127]=C.
static constexpr float QTABc[128] = {
   8.0f,  5.5f,  5.0f,  8.0f, 12.0f, 20.0f, 25.5f, 30.5f,
   6.0f,  6.0f,  7.0f,  9.5f, 13.0f, 29.0f, 30.0f, 27.5f,
   7.0f,  6.5f,  8.0f, 12.0f, 20.0f, 28.5f, 34.5f, 28.0f,
   7.0f,  8.5f, 11.0f, 14.5f, 25.5f, 43.5f, 40.0f, 31.0f,
   9.0f, 11.0f, 18.5f, 28.0f, 34.0f, 54.5f, 51.5f, 38.5f,
  12.0f, 17.5f, 27.5f, 32.0f, 40.5f, 52.0f, 56.5f, 46.0f,
  24.5f, 32.0f, 39.0f, 43.5f, 51.5f, 60.5f, 60.0f, 50.5f,
  36.0f, 46.0f, 47.5f, 49.0f, 56.0f, 50.0f, 51.5f, 49.5f,

   8.5f,  9.0f, 12.0f, 23.5f, 49.5f, 49.5f, 49.5f, 49.5f,
   9.0f, 10.5f, 13.0f, 33.0f, 49.5f, 49.5f, 49.5f, 49.5f,
  12.0f, 13.0f, 28.0f, 49.5f, 49.5f, 49.5f, 49.5f, 49.5f,
  23.5f, 33.0f, 49.5f, 49.5f, 49.5f, 49.5f, 49.5f, 49.5f,
  49.5f, 49.5f, 49.5f, 49.5f, 49.5f, 49.5f, 49.5f, 49.5f,
  49.5f, 49.5f, 49.5f, 49.5f, 49.5f, 49.5f, 49.5f, 49.5f,
  49.5f, 49.5f, 49.5f, 49.5f, 49.5f, 49.5f, 49.5f, 49.5f,
  49.5f, 49.5f, 49.5f, 49.5f, 49.5f, 49.5f, 49.5f, 49.5f,
};

// correctly-rounded f32 ops, no contraction — each maps to one numpy C op
__device__ __forceinline__ float fm(float a, float b) { return __fmul_rn(a, b); }
__device__ __forceinline__ float fa(float a, float b) { return __fadd_rn(a, b); }
__device__ __forceinline__ float fs(float a, float b) { return __fsub_rn(a, b); }
__device__ __forceinline__ float fd(float a, float b) { return __fdiv_rn(a, b); }

typedef float v2f __attribute__((ext_vector_type(2)));
__device__ __forceinline__ v2f mk2(float a, float b) { v2f r; r.x = a; r.y = b; return r; }

// ===== VOP3P packed-FP32 inline asm =====
// v_pk_mul_f32/v_pk_add_f32: two independent correctly-rounded IEEE f32 ops per inst —
// each half is bit-identical to the scalar fm/fa it replaces. R4 showed the compiler
// can't do this well from C (it rematerializes constant pairs as per-op v_movs), so:
//  - the 32 DCT coefficient pairs live as 6 base SGPR pairs ("s" constraint, wave-uniform);
//    swapped/negated variants are expressed with op_sel / neg_lo / neg_hi modifiers
//    (compile-time immediates, zero runtime cost).
//  - scalar broadcasts use op_sel_hi to replicate one half of a packed register.
// PKM: d = s0(pair) * s1(SGPR pair, with modifier string M applying to src1).
// PKMV: d = s0 * s1 (both VGPR pairs, no modifiers).
// PKA: a += p (dataflow-ordered; IEEE add is commutative bitwise for finite/zero values).
#define PKM(d, s0, s1, M) asm("v_pk_mul_f32 %0, %1, %2 " M : "=v"(d) : "v"(s0), "s"(s1))
#define PKMV(d, s0, s1)   asm("v_pk_mul_f32 %0, %1, %2"     : "=v"(d) : "v"(s0), "v"(s1))
#define PKA(a, p)         asm("v_pk_add_f32 %0, %1, %0"     : "+v"(a) : "v"(p))
// src1 modifier strings (src0 stays default op_sel:[0]=0, op_sel_hi:[0]=1):
#define PL   ""
#define SW   "op_sel:[0,1] op_sel_hi:[1,0]"                          // swap src1 halves
#define N2   "neg_lo:[0,1] neg_hi:[0,1]"                             // negate src1 both halves
#define SWN2 "op_sel:[0,1] op_sel_hi:[1,0] neg_lo:[0,1] neg_hi:[0,1]"
#define NH   "neg_hi:[0,1]"                                          // negate src1 in hi half-op
#define NL   "neg_lo:[0,1]"                                          // negate src1 in lo half-op
#define SWNH "op_sel:[0,1] op_sel_hi:[1,0] neg_hi:[0,1]"
#define SWNL "op_sel:[0,1] op_sel_hi:[1,0] neg_lo:[0,1]"

// One workgroup = one 32x32 pixel tile = 3 waves (192 threads).
//   24 DCT blocks (16 Y + 4 Cb + 4 Cr) x 8 rows = 192 row-tasks = ALL waves fully active.
//   blk = tid>>3 → wave = blk>>3: einsum1→einsum2 dependency (Cq) is same-wave only →
//   no __syncthreads between them. Chroma recon aliases the chroma input (same-wave in-order).
//   Einsums run on VOP3P packed FP32 (see above): per-accumulator-half term order is
//   EXACTLY the verified scalar sequence — bit-identical output.
//   LAUNCH BOUNDS (192,4): R2 post-mortem — never request 8 waves/EU (forces VGPR=32, spills).
__global__ __launch_bounds__(192, 4)
void jpeg_kernel(const float* __restrict__ x, float* __restrict__ out) {
  const int tid = threadIdx.x;
  const int q  = blockIdx.x;           // 0..4095
  const int b  = q >> 8;               // image 0..15
  const int qq = q & 255;
  const int row0 = (qq >> 4) << 5;     // 32-px tile row
  const int col0 = (qq & 15) << 5;

  __shared__ __align__(16) float Ys[32][36];    // centered Y, then recon y_r (in-place per wave)
  __shared__ __align__(16) float Cb[16][20];    // subsampled -128, then recon cbm (in-place)
  __shared__ __align__(16) float Cr[16][20];
  __shared__ __align__(16) float Cq[24][8][10]; // quantized coefs; stride 10 → rows 8B-aligned for b64 reads

  // 6 base coefficient pairs — wave-uniform, forced into SGPR pairs by the "s" constraints.
  // All 32 (D[v][2g],D[v][2g+1]) pairs are one of these up to half-swap (SW) and negation (NL/NH/N2).
  const v2f B0 = mk2(0.35355339059327373f, 0.35355339059327373f);
  const v2f B1 = mk2(0.49039264020161522f, 0.41573480615127262f);
  const v2f B2 = mk2(0.27778511650980111f, 0.09754516100806413f);
  const v2f B3 = mk2(0.46193976625564337f, 0.19134171618254489f);
  const v2f B4 = mk2(0.41573480615127262f, 0.09754516100806413f);
  const v2f B5 = mk2(0.49039264020161522f, 0.27778511650980111f);

  // ---------------- Stage 1: load, clip, *255, color convert (strict f32, no FMA) ----------------
  auto stage1 = [&](int qd) {
    const int pr = qd >> 3;
    const int pc = (qd & 7) << 2;
    const size_t ib = ((((size_t)b * 3) * 512 + (size_t)(row0 + pr)) * 512) + (size_t)(col0 + pc);
    float4 rv = *(const float4*)(x + ib);
    float4 gv = *(const float4*)(x + ib + CH_STRIDE);
    float4 bv = *(const float4*)(x + ib + 2 * CH_STRIDE);
    float xr[4] = {rv.x, rv.y, rv.z, rv.w};
    float xg[4] = {gv.x, gv.y, gv.z, gv.w};
    float xb[4] = {bv.x, bv.y, bv.z, bv.w};
    float yo[4], cbv[4], crv[4];
#pragma unroll
    for (int i = 0; i < 4; ++i) {
      float r  = fm(fminf(fmaxf(xr[i], 0.0f), 1.0f), 255.0f);
      float g  = fm(fminf(fmaxf(xg[i], 0.0f), 1.0f), 255.0f);
      float bb = fm(fminf(fmaxf(xb[i], 0.0f), 1.0f), 255.0f);
      float y  = fa(fa(fm(0.299f, r), fm(0.587f, g)), fm(0.114f, bb));
      yo[i]  = fs(y, 128.0f);
      cbv[i] = fa(fa(fs(fm(-0.168736f, r), fm(0.331264f, g)), fm(0.5f, bb)), 128.0f);
      crv[i] = fa(fs(fs(fm(0.5f, r), fm(0.418688f, g)), fm(0.081312f, bb)), 128.0f);
    }
    *(float4*)&Ys[pr][pc] = make_float4(yo[0], yo[1], yo[2], yo[3]);

    // chroma 2x2 mean — pairwise (c00+c01)+(c10+c11), exact /4 as *0.25f (power-of-2, bit-equal)
    float cbh0 = fa(cbv[0], cbv[1]), cbh1 = fa(cbv[2], cbv[3]);
    float crh0 = fa(crv[0], crv[1]), crh1 = fa(crv[2], crv[3]);
    float pcb0 = __shfl_xor(cbh0, 8, 64);   // partner = adjacent pixel row, same cols (same wave)
    float pcb1 = __shfl_xor(cbh1, 8, 64);
    float pcr0 = __shfl_xor(crh0, 8, 64);
    float pcr1 = __shfl_xor(crh1, 8, 64);
    if (((qd >> 3) & 1) == 0) {             // even pixel row: owns the 2x2 output
      const int ii = pr >> 1, jc = pc >> 1;
      Cb[ii][jc]     = fs(fm(fa(cbh0, pcb0), 0.25f), 128.0f);
      Cb[ii][jc + 1] = fs(fm(fa(cbh1, pcb1), 0.25f), 128.0f);
      Cr[ii][jc]     = fs(fm(fa(crh0, pcr0), 0.25f), 128.0f);
      Cr[ii][jc + 1] = fs(fm(fa(crh1, pcr1), 0.25f), 128.0f);
    }
  };
  stage1(tid);
  if (tid < 64) stage1(192 + tid);        // whole wave 0 → shfl pairs stay intact
  __syncthreads();

  // Task mapping: blk = tid>>3 (0..15 Y, 16..19 Cb, 20..23 Cr), j = tid&7 (coef row u / recon row x)
  const int  blk = tid >> 3;
  const int  j   = tid & 7;
  const bool isY = blk < 16;
  const float* src;   // 8x8 block base in LDS
  float*       wdst;  // recon row dest (aliases src buffer; same-wave in-order → safe)
  int ld;
  const float* qr = QTABc + j * 8;
  if (isY) {
    const int by = blk >> 2, bx = blk & 3;
    src = &Ys[by * 8][bx * 8];  wdst = &Ys[by * 8 + j][bx * 8];  ld = 36;
  } else if (blk < 20) {
    const int c = blk - 16, cy = c >> 1, cx = c & 1;
    src = &Cb[cy * 8][cx * 8];  wdst = &Cb[cy * 8 + j][cx * 8];  ld = 20;  qr += 64;
  } else {
    const int c = blk - 20, cy = c >> 1, cx = c & 1;
    src = &Cr[cy * 8][cx * 8];  wdst = &Cr[cy * 8 + j][cx * 8];  ld = 20;  qr += 64;
  }

  // ======= einsum1 'bhwxy,ux,vy->bhwuv' — packed VOP3P, bit-identical term order =======
  // Scalar reference per accumulator s_l (l=0..3), per v: m=0..15: s_l += t0[4m+l]*D[v][(4m+l)&7],
  // t0[8xx+yy] = fl(blk[xx][yy]*D[j][xx]); coef = fl(fl(s0+s1)+fl(s2+s3)).
  // Packed: sA[v]=(s0,s1), sB[v]=(s2,s3). Per xx: sA += t01*(Dv0,Dv1); sA += t45*(Dv4,Dv5);
  // sB += t23*(Dv2,Dv3); sB += t67*(Dv6,Dv7) — each half's sequence is exactly m=0..15. ✓
  {
    float dj[8];
#pragma unroll
    for (int xx = 0; xx < 8; ++xx) dj[xx] = DMc[j][xx];
    v2f sA[8], sB[8];
#pragma unroll
    for (int v = 0; v < 8; ++v) { sA[v] = mk2(0.0f, 0.0f); sB[v] = mk2(0.0f, 0.0f); }
    const float* srow = src;
#pragma unroll
    for (int xx = 0; xx < 8; ++xx) {
      v2f a01 = *(const v2f*)(srow);
      v2f a23 = *(const v2f*)(srow + 2);
      v2f a45 = *(const v2f*)(srow + 4);
      v2f a67 = *(const v2f*)(srow + 6);
      srow += ld;
      v2f djp = mk2(dj[xx], dj[xx]);
      v2f t01, t23, t45, t67, p;
      PKMV(t01, a01, djp);  PKMV(t23, a23, djp);
      PKMV(t45, a45, djp);  PKMV(t67, a67, djp);
      // v=0: row (a,a,a,a,a,a,a,a) → B0 plain everywhere
      PKM(p, t01, B0, PL);   PKA(sA[0], p);
      PKM(p, t23, B0, PL);   PKA(sB[0], p);
      PKM(p, t45, B0, PL);   PKA(sA[0], p);
      PKM(p, t67, B0, PL);   PKA(sB[0], p);
      // v=1: (.49,.42 | .28,.098 | -.098,-.28 | -.42,-.49)
      PKM(p, t01, B1, PL);   PKA(sA[1], p);
      PKM(p, t23, B2, PL);   PKA(sB[1], p);
      PKM(p, t45, B2, SWN2); PKA(sA[1], p);
      PKM(p, t67, B1, SWN2); PKA(sB[1], p);
      // v=2: (.46,.19 | -.19,-.46 | -.46,-.19 | .19,.46)
      PKM(p, t01, B3, PL);   PKA(sA[2], p);
      PKM(p, t23, B3, SWN2); PKA(sB[2], p);
      PKM(p, t45, B3, N2);   PKA(sA[2], p);
      PKM(p, t67, B3, SW);   PKA(sB[2], p);
      // v=3: (.42,-.098 | -.49,-.28 | .28,.49 | .098,-.42)
      PKM(p, t01, B4, NH);   PKA(sA[3], p);
      PKM(p, t23, B5, N2);   PKA(sB[3], p);
      PKM(p, t45, B5, SW);   PKA(sA[3], p);
      PKM(p, t67, B4, SWNH); PKA(sB[3], p);
      // v=4: (a,-a | -a,a | a,-a | -a,a)
      PKM(p, t01, B0, NH);   PKA(sA[4], p);
      PKM(p, t23, B0, NL);   PKA(sB[4], p);
      PKM(p, t45, B0, NH);   PKA(sA[4], p);
      PKM(p, t67, B0, NL);   PKA(sB[4], p);
      // v=5: (.28,-.49 | .098,.42 | -.42,-.098 | .49,-.28)
      PKM(p, t01, B5, SWNH); PKA(sA[5], p);
      PKM(p, t23, B4, SW);   PKA(sB[5], p);
      PKM(p, t45, B4, N2);   PKA(sA[5], p);
      PKM(p, t67, B5, NH);   PKA(sB[5], p);
      // v=6: (.19,-.46 | .46,-.19 | -.19,.46 | -.46,.19)
      PKM(p, t01, B3, SWNH); PKA(sA[6], p);
      PKM(p, t23, B3, NH);   PKA(sB[6], p);
      PKM(p, t45, B3, SWNL); PKA(sA[6], p);
      PKM(p, t67, B3, NL);   PKA(sB[6], p);
      // v=7: (.098,-.28 | .42,-.49 | .49,-.42 | .28,-.098)
      PKM(p, t01, B2, SWNH); PKA(sA[7], p);
      PKM(p, t23, B1, SWNH); PKA(sB[7], p);
      PKM(p, t45, B1, NH);   PKA(sA[7], p);
      PKM(p, t67, B2, NH);   PKA(sB[7], p);
    }
    float* cq = &Cq[blk][j][0];
#pragma unroll
    for (int v = 0; v < 8; ++v) {
      float coef = fa(fa(sA[v].x, sA[v].y), fa(sB[v].x, sB[v].y));   // hadd tree
      float qv = qr[v];
      cq[v] = fm(rintf(fd(coef, qv)), qv);                           // round half-even, f32 div
    }
  }

  // Cq[blk] producers and consumers are the SAME wave: per-wave LDS ops complete in order —
  // compiler fence + drain of our own ds ops, no block barrier.
  asm volatile("s_waitcnt lgkmcnt(0)" ::: "memory");

  // ======= einsum2 'bhwuv,ux,vy->bhwxy' — packed VOP3P, bit-identical term order =======
  // Scalar reference: per u: t2r[v]=fl(coef[u][v]*D[u][x=j]); per yy: v=0..7:
  // acc[yy] += t2r[v]*D[v][yy]. Packed: accP[t]=(acc[2t],acc[2t+1]); q_g=(t2r[2g],t2r[2g+1])
  // computed packed; per v (in order), per t: accP[t] += bcast(t2r[v]) * (Dv_{2t},Dv_{2t+1}).
  // bcast via src0 op_sel: v even → both halves read q's lo; v odd → both read hi. ✓
  {
    float dcol[8];
    const float* dct = &DMcT[j][0];
#pragma unroll
    for (int u = 0; u < 8; ++u) dcol[u] = dct[u];    // DMc[u][j]
    v2f accP[4];
#pragma unroll
    for (int t = 0; t < 4; ++t) accP[t] = mk2(0.0f, 0.0f);
    const float* cqb = &Cq[blk][0][0];
#pragma unroll
    for (int u = 0; u < 8; ++u) {
      v2f c01 = *(const v2f*)(cqb + u * 10);
      v2f c23 = *(const v2f*)(cqb + u * 10 + 2);
      v2f c45 = *(const v2f*)(cqb + u * 10 + 4);
      v2f c67 = *(const v2f*)(cqb + u * 10 + 6);
      v2f dup = mk2(dcol[u], dcol[u]);
      v2f q0, q1, q2, q3, p;
      PKMV(q0, c01, dup);  PKMV(q1, c23, dup);   // (t2r0,t2r1) (t2r2,t2r3)
      PKMV(q2, c45, dup);  PKMV(q3, c67, dup);   // (t2r4,t2r5) (t2r6,t2r7)
      // v=0 (bcast lo of q0), row pairs: B0,B0,B0,B0
      PKM(p, q0, B0, "op_sel:[0,0] op_sel_hi:[0,1]"); PKA(accP[0], p);
      PKM(p, q0, B0, "op_sel:[0,0] op_sel_hi:[0,1]"); PKA(accP[1], p);
      PKM(p, q0, B0, "op_sel:[0,0] op_sel_hi:[0,1]"); PKA(accP[2], p);
      PKM(p, q0, B0, "op_sel:[0,0] op_sel_hi:[0,1]"); PKA(accP[3], p);
      // v=1 (bcast hi of q0): B1, B2, SWN2 B2, SWN2 B1
      PKM(p, q0, B1, "op_sel:[1,0] op_sel_hi:[1,1]"); PKA(accP[0], p);
      PKM(p, q0, B2, "op_sel:[1,0] op_sel_hi:[1,1]"); PKA(accP[1], p);
      PKM(p, q0, B2, "op_sel:[1,1] op_sel_hi:[1,0] neg_lo:[0,1] neg_hi:[0,1]"); PKA(accP[2], p);
      PKM(p, q0, B1, "op_sel:[1,1] op_sel_hi:[1,0] neg_lo:[0,1] neg_hi:[0,1]"); PKA(accP[3], p);
      // v=2 (bcast lo of q1): B3, SWN2 B3, N2 B3, SW B3
      PKM(p, q1, B3, "op_sel:[0,0] op_sel_hi:[0,1]"); PKA(accP[0], p);
      PKM(p, q1, B3, "op_sel:[0,1] op_sel_hi:[0,0] neg_lo:[0,1] neg_hi:[0,1]"); PKA(accP[1], p);
      PKM(p, q1, B3, "op_sel:[0,0] op_sel_hi:[0,1] neg_lo:[0,1] neg_hi:[0,1]"); PKA(accP[2], p);
      PKM(p, q1, B3, "op_sel:[0,1] op_sel_hi:[0,0]"); PKA(accP[3], p);
      // v=3 (bcast hi of q1): NH B4, N2 B5, SW B5, SWNH B4
      PKM(p, q1, B4, "op_sel:[1,0] op_sel_hi:[1,1] neg_hi:[0,1]"); PKA(accP[0], p);
      PKM(p, q1, B5, "op_sel:[1,0] op_sel_hi:[1,1] neg_lo:[0,1] neg_hi:[0,1]"); PKA(accP[1], p);
      PKM(p, q1, B5, "op_sel:[1,1] op_sel_hi:[1,0]"); PKA(accP[2], p);
      PKM(p, q1, B4, "op_sel:[1,1] op_sel_hi:[1,0] neg_hi:[0,1]"); PKA(accP[3], p);
      // v=4 (bcast lo of q2): NH B0, NL B0, NH B0, NL B0
      PKM(p, q2, B0, "op_sel:[0,0] op_sel_hi:[0,1] neg_hi:[0,1]"); PKA(accP[0], p);
      PKM(p, q2, B0, "op_sel:[0,0] op_sel_hi:[0,1] neg_lo:[0,1]"); PKA(accP[1], p);
      PKM(p, q2, B0, "op_sel:[0,0] op_sel_hi:[0,1] neg_hi:[0,1]"); PKA(accP[2], p);
      PKM(p, q2, B0, "op_sel:[0,0] op_sel_hi:[0,1] neg_lo:[0,1]"); PKA(accP[3], p);
      // v=5 (bcast hi of q2): SWNH B5, SW B4, N2 B4, NH B5
      PKM(p, q2, B5, "op_sel:[1,1] op_sel_hi:[1,0] neg_hi:[0,1]"); PKA(accP[0], p);
      PKM(p, q2, B4, "op_sel:[1,1] op_sel_hi:[1,0]"); PKA(accP[1], p);
      PKM(p, q2, B4, "op_sel:[1,0] op_sel_hi:[1,1] neg_lo:[0,1] neg_hi:[0,1]"); PKA(accP[2], p);
      PKM(p, q2, B5, "op_sel:[1,0] op_sel_hi:[1,1] neg_hi:[0,1]"); PKA(accP[3], p);
      // v=6 (bcast lo of q3): SWNH B3, NH B3, SWNL B3, NL B3
      PKM(p, q3, B3, "op_sel:[0,1] op_sel_hi:[0,0] neg_hi:[0,1]"); PKA(accP[0], p);
      PKM(p, q3, B3, "op_sel:[0,0] op_sel_hi:[0,1] neg_hi:[0,1]"); PKA(accP[1], p);
      PKM(p, q3, B3, "op_sel:[0,1] op_sel_hi:[0,0] neg_lo:[0,1]"); PKA(accP[2], p);
      PKM(p, q3, B3, "op_sel:[0,0] op_sel_hi:[0,1] neg_lo:[0,1]"); PKA(accP[3], p);
      // v=7 (bcast hi of q3): SWNH B2, SWNH B1, NH B1, NH B2
      PKM(p, q3, B2, "op_sel:[1,1] op_sel_hi:[1,0] neg_hi:[0,1]"); PKA(accP[0], p);
      PKM(p, q3, B1, "op_sel:[1,1] op_sel_hi:[1,0] neg_hi:[0,1]"); PKA(accP[1], p);
      PKM(p, q3, B1, "op_sel:[1,0] op_sel_hi:[1,1] neg_hi:[0,1]"); PKA(accP[2], p);
      PKM(p, q3, B2, "op_sel:[1,0] op_sel_hi:[1,1] neg_hi:[0,1]"); PKA(accP[3], p);
    }
    float r0[8];
#pragma unroll
    for (int t = 0; t < 4; ++t) {
      float recA = fa(accP[t].x, 128.0f);
      float recB = fa(accP[t].y, 128.0f);
      r0[2 * t]     = isY ? recA : fs(recA, 128.0f);                 // y_r  /  cbm = cb_u - 128
      r0[2 * t + 1] = isY ? recB : fs(recB, 128.0f);
    }
    *(float4*)(wdst)     = make_float4(r0[0], r0[1], r0[2], r0[3]);
    *(float4*)(wdst + 4) = make_float4(r0[4], r0[5], r0[6], r0[7]);
  }
  __syncthreads();

  // ---------------- Stage 5: upsample, YCbCr->RGB (strict), clip, /255, wrapper ----------------
  auto stage5 = [&](int qd) {
    const int pr = qd >> 3;
    const int pc = (qd & 7) << 2;
    const size_t ib = ((((size_t)b * 3) * 512 + (size_t)(row0 + pr)) * 512) + (size_t)(col0 + pc);
    float4 rv = *(const float4*)(x + ib);          // re-load x (L1/L2-hot)
    float4 gv = *(const float4*)(x + ib + CH_STRIDE);
    float4 bv = *(const float4*)(x + ib + 2 * CH_STRIDE);
    float xr[4] = {rv.x, rv.y, rv.z, rv.w};
    float xg[4] = {gv.x, gv.y, gv.z, gv.w};
    float xb[4] = {bv.x, bv.y, bv.z, bv.w};
    float ro[4], go[4], bo[4];
    const int hr = pr >> 1;
#pragma unroll
    for (int i = 0; i < 4; ++i) {
      float y_r = Ys[pr][pc + i];
      float cbm = Cb[hr][(pc + i) >> 1];
      float crm = Cr[hr][(pc + i) >> 1];
      float r2 = fa(y_r, fm(1.402f, crm));
      float g2 = fs(fs(y_r, fm(0.344136f, cbm)), fm(0.714136f, crm));
      float b2 = fa(y_r, fm(1.772f, cbm));
      float jr = fd(fminf(fmaxf(r2, 0.0f), 255.0f), 255.0f);
      float jg = fd(fminf(fmaxf(g2, 0.0f), 255.0f), 255.0f);
      float jb = fd(fminf(fmaxf(b2, 0.0f), 255.0f), 255.0f);
      ro[i] = fa(xr[i], fs(jr, xr[i]));   // x + (jpeg - x), original unclipped x
      go[i] = fa(xg[i], fs(jg, xg[i]));
      bo[i] = fa(xb[i], fs(jb, xb[i]));
    }
    *(float4*)(out + ib)                 = make_float4(ro[0], ro[1], ro[2], ro[3]);
    *(float4*)(out + ib + CH_STRIDE)     = make_float4(go[0], go[1], go[2], go[3]);
    *(float4*)(out + ib + 2 * CH_STRIDE) = make_float4(bo[0], bo[1], bo[2], bo[3]);
  };
  stage5(tid);
  if (tid < 64) stage5(192 + tid);
}

extern "C" void kernel_launch(void* const* d_in, const int* in_sizes, int n_in,
                              void* d_out, int out_size, void* d_ws, size_t ws_size,
                              hipStream_t stream) {
  const float* x = (const float*)d_in[0];
  float* out = (float*)d_out;
  jpeg_kernel<<<dim3(4096), dim3(192), 0, stream>>>(x, out);
}